// Round 4
// baseline (273.066 us; speedup 1.0000x reference)
//
#include <hip/hip_runtime.h>

#define N_NODES   50000
#define HID       64
#define N_GRAPHS  128
#define N_CLASSES 10
#define NP        196           // partitions of 256 nodes (196*256 = 50176)
#define EPA       8192          // edges per bucket block (r0-proven)
#define PCAP      8192          // per-partition capacity in packed[] (>20 sigma)

typedef __attribute__((ext_vector_type(8))) short short8;
typedef __attribute__((ext_vector_type(4))) float f32x4;

__device__ __forceinline__ unsigned bf16rne(float f) {
    unsigned u = __float_as_uint(f);
    return (u + 0x7fffu + ((u >> 16) & 1u)) >> 16;
}
__device__ __forceinline__ unsigned pack_bf16x2(float lo, float hi) {
    return bf16rne(lo) | (bf16rne(hi) << 16);
}

// Features are row-major bf16 [node][64] (r6-proven fastest layout).

// ---------------- x -> bf16 conversion + gcursor zero + gstart ------------
// gstart[g] = first node of graph g (batch is sorted); gstart[128] = N.
// Replaces final_kernel's 34 serially-dependent binary-search loads.

__global__ void cvt_kernel(const float* __restrict__ x, unsigned short* __restrict__ xb,
                           int* __restrict__ gcursor, const int* __restrict__ batch,
                           int* __restrict__ gstart) {
    int i = blockIdx.x * blockDim.x + threadIdx.x;
    if (blockIdx.x == 0 && threadIdx.x < NP) gcursor[threadIdx.x] = 0;
    if (i < N_NODES) {
        int b = batch[i];
        int bp = (i > 0) ? batch[i - 1] : -1;
        for (int g = bp + 1; g <= b; ++g) gstart[g] = i;       // ~128 writes total
        if (i == N_NODES - 1)
            for (int g = b + 1; g <= N_GRAPHS; ++g) gstart[g] = N_NODES;
    }
    if (i < N_NODES * 16) {
        float4 v = ((const float4*)x)[i];
        uint2 o;
        o.x = pack_bf16x2(v.x, v.y);
        o.y = pack_bf16x2(v.z, v.w);
        ((uint2*)xb)[i] = o;
    }
}

// ---------------- CSR build: 2-level LDS-staged counting sort -------------
// (r2 lesson: flat atomic scatter = 90us of random-RMW; keep the LDS sort.)

__global__ __launch_bounds__(256) void bucket_kernel(
    const int* __restrict__ src, const int* __restrict__ dst,
    int* __restrict__ gcursor, unsigned* __restrict__ packed, int E) {
    __shared__ int hist[NP], scp[NP], base[NP], cnt2[NP];
    __shared__ int sc[256];
    __shared__ unsigned stag[EPA];
    const int t = threadIdx.x;
    const int e0 = blockIdx.x * EPA;
    const int e1 = min(e0 + EPA, E);
    for (int i = t; i < NP; i += 256) { hist[i] = 0; cnt2[i] = 0; }
    __syncthreads();
    for (int e = e0 + t; e < e1; e += 256)
        atomicAdd(&hist[dst[e] >> 8], 1);
    __syncthreads();
    sc[t] = (t < NP) ? hist[t] : 0;
    __syncthreads();
    for (int off = 1; off < 256; off <<= 1) {
        int add = (t >= off) ? sc[t - off] : 0;
        __syncthreads();
        sc[t] += add;
        __syncthreads();
    }
    if (t < NP) {
        scp[t] = sc[t] - hist[t];
        if (hist[t] > 0) base[t] = atomicAdd(&gcursor[t], hist[t]);
    }
    __syncthreads();
    for (int e = e0 + t; e < e1; e += 256) {
        int d = dst[e], s = src[e];
        int p = d >> 8;
        int idx = scp[p] + atomicAdd(&cnt2[p], 1);
        stag[idx] = (unsigned)s | ((unsigned)(d & 255) << 16) | ((unsigned)p << 24);
    }
    __syncthreads();
    const int n = e1 - e0;
    for (int i = t; i < n; i += 256) {
        unsigned v = stag[i];
        int p = v >> 24;
        packed[(size_t)p * PCAP + base[p] + (i - scp[p])] = v & 0x00FFFFFFu;
    }
}

// One block per partition. Integrated pscan, node offsets, LDS csr scatter,
// coalesced copy out. Block 0 also zeroes sums for the fused pooling.
__global__ __launch_bounds__(256) void build_kernel(
    const unsigned* __restrict__ packed, const int* __restrict__ gcursor,
    int* __restrict__ offsets, unsigned short* __restrict__ csr,
    int* __restrict__ sums_zero) {
    __shared__ int hist[256], lofs[256], cnt[256], sc[256], gv[256];
    __shared__ unsigned short lcsr[PCAP];
    const int p = blockIdx.x, t = threadIdx.x;

    if (p == 0) {   // zero sums(128*64 f32) for linear3's fused pooling
        for (int i = t; i < N_GRAPHS * 64; i += 256) sums_zero[i] = 0;
    }

    int v = (t < NP) ? gcursor[t] : 0;
    sc[t] = v; gv[t] = v;
    __syncthreads();
    for (int off = 1; off < 256; off <<= 1) {
        int add = (t >= off) ? sc[t - off] : 0;
        __syncthreads();
        sc[t] += add;
        __syncthreads();
    }
    const int pb = sc[p] - gv[p];          // exclusive prefix at p
    const int ne = gv[p];
    if (p == NP - 1 && t == 0) offsets[N_NODES] = sc[NP - 1];
    __syncthreads();

    const unsigned* mypk = packed + (size_t)p * PCAP;
    hist[t] = 0; cnt[t] = 0;
    __syncthreads();
    for (int i = t; i < ne; i += 256)
        atomicAdd(&hist[(mypk[i] >> 16) & 255], 1);
    __syncthreads();
    sc[t] = hist[t];
    __syncthreads();
    for (int off = 1; off < 256; off <<= 1) {
        int add = (t >= off) ? sc[t - off] : 0;
        __syncthreads();
        sc[t] += add;
        __syncthreads();
    }
    lofs[t] = sc[t] - hist[t];
    int node = p * 256 + t;
    if (node < N_NODES) offsets[node] = pb + lofs[t];
    __syncthreads();
    for (int i = t; i < ne; i += 256) {
        unsigned vv = mypk[i];
        int dl = (vv >> 16) & 255;
        int slot = lofs[dl] + atomicAdd(&cnt[dl], 1);
        lcsr[slot] = (unsigned short)(vv & 0xFFFFu);
    }
    __syncthreads();
    for (int i = t; i < ne; i += 256) csr[pb + i] = lcsr[i];
}

// ---------------- Gather: one wave per TWO nodes, 32+32-edge rounds -------
// Latency theory (r0/r1: address-count-insensitive => latency-bound): double
// the in-flight loads per wave. 8 independent dwordx4 row-loads per round
// (4 for node A, 4 for node B); one 64-lane csr load feeds both.

__global__ __launch_bounds__(256) void gather_kernel(
    const unsigned short* __restrict__ hin,
    const int* __restrict__ offsets, const unsigned short* __restrict__ csr_src,
    unsigned short* __restrict__ agg) {
    const int w = threadIdx.x >> 6, lane = threadIdx.x & 63;
    const int rg = lane >> 3;          // row group: 8 rows per load instr
    const int cg = lane & 7;           // channel group: 8 ch (16 B) per lane
    const int n0 = (blockIdx.x * 4 + w) * 2;   // two consecutive nodes
    const int begA = offsets[n0];
    const int endA = offsets[n0 + 1];
    const int endB = offsets[n0 + 2];

    float accA[8] = {0.f,0.f,0.f,0.f,0.f,0.f,0.f,0.f};
    float accB[8] = {0.f,0.f,0.f,0.f,0.f,0.f,0.f,0.f};
    int eA = begA, eB = endA;
    while (eA < endA || eB < endB) {
        int cntA = endA - eA; cntA = (cntA > 32) ? 32 : cntA;
        int cntB = endB - eB; cntB = (cntB > 32) ? 32 : cntB;
        int idx;
        if (lane < 32) idx = (lane < cntA) ? (int)csr_src[eA + lane] : 0;
        else           idx = ((lane - 32) < cntB) ? (int)csr_src[eB + (lane - 32)] : 0;
        uint4 uA[4], uB[4];
#pragma unroll
        for (int p = 0; p < 4; ++p) {
            int e = 8 * p + rg;
            int rA = __shfl(idx, e);
            uA[p] = (e < cntA) ? *((const uint4*)(hin + (size_t)rA * 64) + cg)
                               : make_uint4(0u, 0u, 0u, 0u);
        }
#pragma unroll
        for (int p = 0; p < 4; ++p) {
            int e = 8 * p + rg;
            int rB = __shfl(idx, 32 + e);
            uB[p] = (e < cntB) ? *((const uint4*)(hin + (size_t)rB * 64) + cg)
                               : make_uint4(0u, 0u, 0u, 0u);
        }
#pragma unroll
        for (int p = 0; p < 4; ++p) {
            accA[0] += __uint_as_float(uA[p].x << 16);
            accA[1] += __uint_as_float(uA[p].x & 0xffff0000u);
            accA[2] += __uint_as_float(uA[p].y << 16);
            accA[3] += __uint_as_float(uA[p].y & 0xffff0000u);
            accA[4] += __uint_as_float(uA[p].z << 16);
            accA[5] += __uint_as_float(uA[p].z & 0xffff0000u);
            accA[6] += __uint_as_float(uA[p].w << 16);
            accA[7] += __uint_as_float(uA[p].w & 0xffff0000u);
            accB[0] += __uint_as_float(uB[p].x << 16);
            accB[1] += __uint_as_float(uB[p].x & 0xffff0000u);
            accB[2] += __uint_as_float(uB[p].y << 16);
            accB[3] += __uint_as_float(uB[p].y & 0xffff0000u);
            accB[4] += __uint_as_float(uB[p].z << 16);
            accB[5] += __uint_as_float(uB[p].z & 0xffff0000u);
            accB[6] += __uint_as_float(uB[p].w << 16);
            accB[7] += __uint_as_float(uB[p].w & 0xffff0000u);
        }
        eA += cntA; eB += cntB;
    }
    // reduce over row groups (lane bits 3..5); all lanes end with totals
#pragma unroll
    for (int m = 8; m <= 32; m <<= 1)
#pragma unroll
        for (int j = 0; j < 8; ++j) {
            accA[j] += __shfl_xor(accA[j], m);
            accB[j] += __shfl_xor(accB[j], m);
        }
    if (rg == 0) {
        uint4 o;
        o.x = pack_bf16x2(accA[0], accA[1]);
        o.y = pack_bf16x2(accA[2], accA[3]);
        o.z = pack_bf16x2(accA[4], accA[5]);
        o.w = pack_bf16x2(accA[6], accA[7]);
        *((uint4*)(agg + (size_t)n0 * 64) + cg) = o;
    } else if (rg == 1) {
        uint4 o;
        o.x = pack_bf16x2(accB[0], accB[1]);
        o.y = pack_bf16x2(accB[2], accB[3]);
        o.z = pack_bf16x2(accB[4], accB[5]);
        o.w = pack_bf16x2(accB[6], accB[7]);
        *((uint4*)(agg + (size_t)(n0 + 1) * 64) + cg) = o;
    }
}

// ---------------- Linear: streaming MFMA (row-major, r6-proven) ----------
// POOL=1 (layer 3): skip h3 entirely; pool D-fragments straight from regs.
// D layout: node = q*4 + r, channel = t*16 + c  (C/D col=lane&15 = B-col).

template <int RELU, int POOL>
__global__ __launch_bounds__(256) void linear_kernel(
    const unsigned short* __restrict__ agg,
    const unsigned short* __restrict__ hin,
    const float* __restrict__ Wrel, const float* __restrict__ bias,
    const float* __restrict__ Wroot, unsigned short* __restrict__ hout,
    const int* __restrict__ batch, float* __restrict__ sums) {
    const int tid = threadIdx.x;
    const int w = tid >> 6, lane = tid & 63;
    const int q = lane >> 4, c = lane & 15;
    const int g0 = (blockIdx.x * 4 + w) * 16;
    if (g0 >= N_NODES) return;

    // weight B-fragments: B[k][o], o = t*16+c, k = s*32+q*8+j
    short8 brel[4][2], broot[4][2];
    float biasv[4];
#pragma unroll
    for (int t = 0; t < 4; ++t) {
        int o = t * 16 + c;
        biasv[t] = bias[o];
#pragma unroll
        for (int s = 0; s < 2; ++s) {
            const float4* pr = (const float4*)(Wrel  + o * 64 + s * 32 + q * 8);
            const float4* po = (const float4*)(Wroot + o * 64 + s * 32 + q * 8);
            float4 r0 = pr[0], r1 = pr[1], z0 = po[0], z1 = po[1];
            short8 rr, zz;
            rr[0] = (short)bf16rne(r0.x); rr[1] = (short)bf16rne(r0.y);
            rr[2] = (short)bf16rne(r0.z); rr[3] = (short)bf16rne(r0.w);
            rr[4] = (short)bf16rne(r1.x); rr[5] = (short)bf16rne(r1.y);
            rr[6] = (short)bf16rne(r1.z); rr[7] = (short)bf16rne(r1.w);
            zz[0] = (short)bf16rne(z0.x); zz[1] = (short)bf16rne(z0.y);
            zz[2] = (short)bf16rne(z0.z); zz[3] = (short)bf16rne(z0.w);
            zz[4] = (short)bf16rne(z1.x); zz[5] = (short)bf16rne(z1.y);
            zz[6] = (short)bf16rne(z1.z); zz[7] = (short)bf16rne(z1.w);
            brel[t][s] = rr; broot[t][s] = zz;
        }
    }

    // A fragments straight from global: A[m=c][k=s*32+q*8+j]
    const int na = min(g0 + c, N_NODES - 1);
    short8 a_agg[2], a_x[2];
#pragma unroll
    for (int s = 0; s < 2; ++s) {
        a_agg[s] = *(const short8*)(agg + (size_t)na * 64 + s * 32 + q * 8);
        a_x[s]   = *(const short8*)(hin + (size_t)na * 64 + s * 32 + q * 8);
    }

    f32x4 acc4[4];
#pragma unroll
    for (int t = 0; t < 4; ++t) {
        f32x4 a0 = {biasv[t], biasv[t], biasv[t], biasv[t]};
        a0 = __builtin_amdgcn_mfma_f32_16x16x32_bf16(a_agg[0], brel[t][0], a0, 0, 0, 0);
        a0 = __builtin_amdgcn_mfma_f32_16x16x32_bf16(a_agg[1], brel[t][1], a0, 0, 0, 0);
        a0 = __builtin_amdgcn_mfma_f32_16x16x32_bf16(a_x[0],  broot[t][0], a0, 0, 0, 0);
        a0 = __builtin_amdgcn_mfma_f32_16x16x32_bf16(a_x[1],  broot[t][1], a0, 0, 0, 0);
        acc4[t] = a0;
    }

    if (POOL) {
        // batch sorted: wave's 16 nodes almost always one graph
        int b0 = batch[g0], b15 = batch[g0 + 15];
        if (b0 == b15) {
#pragma unroll
            for (int t = 0; t < 4; ++t) {
                float s = acc4[t][0] + acc4[t][1] + acc4[t][2] + acc4[t][3];
                s += __shfl_xor(s, 16);          // sum over q (lane bits 4-5)
                s += __shfl_xor(s, 32);
                if (q == 0) atomicAdd(&sums[b0 * 64 + t * 16 + c], s);
            }
        } else {                                  // graph boundary (~4% waves)
#pragma unroll
            for (int r = 0; r < 4; ++r) {
                int bq = batch[g0 + q * 4 + r];
#pragma unroll
                for (int t = 0; t < 4; ++t)
                    atomicAdd(&sums[bq * 64 + t * 16 + c], acc4[t][r]);
            }
        }
    } else {
        // ReLU + bf16 + per-wave LDS transpose (node=q*4+r, ch=t*16+c)
        __shared__ unsigned short outT[4][16][72];
#pragma unroll
        for (int t = 0; t < 4; ++t)
#pragma unroll
            for (int r = 0; r < 4; ++r) {
                float v = acc4[t][r];
                if (RELU) v = fmaxf(v, 0.f);
                outT[w][q * 4 + r][t * 16 + c] = (unsigned short)bf16rne(v);
            }
        // same-wave LDS RAW: compiler emits lgkmcnt wait; no barrier needed
#pragma unroll
        for (int it = 0; it < 2; ++it) {
            int row = it * 8 + (lane >> 3);
            int ch = (lane & 7) * 8;
            int n = g0 + row;
            if (n < N_NODES) {
                short8 v = *(const short8*)&outT[w][row][ch];
                *(short8*)(hout + (size_t)n * 64 + ch) = v;
            }
        }
    }
}

// ---------------- Final: counts from gstart (no binary search) ------------

__global__ void final_kernel(const float* __restrict__ sums, const int* __restrict__ gstart,
                             const float* __restrict__ Wlin, const float* __restrict__ blin,
                             float* __restrict__ out) {
    __shared__ float pl[64];
    int g = blockIdx.x, lane = threadIdx.x;
    float cdiv = fmaxf((float)(gstart[g + 1] - gstart[g]), 1.0f);
    float p = sums[g * 64 + lane] / cdiv;
    out[g * 64 + lane] = p;               // pooled output
    pl[lane] = p;
    __syncthreads();
    if (lane < N_CLASSES) {
        float o = blin[lane];
#pragma unroll
        for (int k = 0; k < 64; ++k) o += pl[k] * Wlin[lane * 64 + k];
        out[N_GRAPHS * 64 + g * N_CLASSES + lane] = o;  // classifier output
    }
}

// ---------------- Launch (10 dispatches, no memsets) ----------------

extern "C" void kernel_launch(void* const* d_in, const int* in_sizes, int n_in,
                              void* d_out, int out_size, void* d_ws, size_t ws_size,
                              hipStream_t stream) {
    const float* x     = (const float*)d_in[0];
    const int*   ei    = (const int*)d_in[1];
    const int*   batch = (const int*)d_in[2];
    const float* W1r = (const float*)d_in[3];
    const float* b1  = (const float*)d_in[4];
    const float* W1o = (const float*)d_in[5];
    const float* W2r = (const float*)d_in[6];
    const float* b2  = (const float*)d_in[7];
    const float* W2o = (const float*)d_in[8];
    const float* W3r = (const float*)d_in[9];
    const float* b3  = (const float*)d_in[10];
    const float* W3o = (const float*)d_in[11];
    const float* Wl  = (const float*)d_in[12];
    const float* bl  = (const float*)d_in[13];
    float* out = (float*)d_out;

    const int E = in_sizes[1] / 2;
    const int* src = ei;
    const int* dst = ei + E;

    char* p = (char*)d_ws;
    unsigned short* xb  = (unsigned short*)p; p += (size_t)N_NODES * 64 * 2;
    unsigned short* h1  = (unsigned short*)p; p += (size_t)N_NODES * 64 * 2;
    unsigned short* h2  = (unsigned short*)p; p += (size_t)N_NODES * 64 * 2;
    unsigned short* agg = (unsigned short*)p; p += (size_t)N_NODES * 64 * 2;
    unsigned* packed    = (unsigned*)p; p += (size_t)NP * PCAP * 4;
    unsigned short* csr = (unsigned short*)p; p += (size_t)E * 2;
    int* offsets   = (int*)p;   p += (size_t)(N_NODES + 1) * 4;
    int* gcursor   = (int*)p;   p += NP * 4;
    float* sums    = (float*)p; p += (size_t)N_GRAPHS * 64 * 4;
    int* gstart    = (int*)p;   p += (N_GRAPHS + 1) * 4;

    const int NCHUNK = (E + EPA - 1) / EPA;  // 153
    cvt_kernel<<<(N_NODES * 16 + 255) / 256, 256, 0, stream>>>(x, xb, gcursor, batch, gstart);
    bucket_kernel<<<NCHUNK, 256, 0, stream>>>(src, dst, gcursor, packed, E);
    build_kernel<<<NP, 256, 0, stream>>>(packed, gcursor, offsets, csr, (int*)sums);

    const int GB = N_NODES / 8;            // 6250 blocks, 1 wave per 2 nodes
    const int LB = (N_NODES + 63) / 64;    // 782 blocks
    gather_kernel<<<GB, 256, 0, stream>>>(xb, offsets, csr, agg);
    linear_kernel<1, 0><<<LB, 256, 0, stream>>>(agg, xb, W1r, b1, W1o, h1, batch, sums);
    gather_kernel<<<GB, 256, 0, stream>>>(h1, offsets, csr, agg);
    linear_kernel<1, 0><<<LB, 256, 0, stream>>>(agg, h1, W2r, b2, W2o, h2, batch, sums);
    gather_kernel<<<GB, 256, 0, stream>>>(h2, offsets, csr, agg);
    linear_kernel<0, 1><<<LB, 256, 0, stream>>>(agg, h2, W3r, b3, W3o, h1, batch, sums);

    final_kernel<<<N_GRAPHS, 64, 0, stream>>>(sums, gstart, Wl, bl, out);
}

// Round 5
// 250.782 us; speedup vs baseline: 1.0889x; 1.0889x over previous
//
#include <hip/hip_runtime.h>

#define N_NODES   50000
#define HID       64
#define N_GRAPHS  128
#define N_CLASSES 10
#define NP        196           // partitions of 256 nodes (196*256 = 50176)
#define EPA       8192          // edges per bucket block (r0-proven)
#define PCAP      8192          // per-partition capacity in packed[] (>20 sigma)

typedef __attribute__((ext_vector_type(8))) short short8;
typedef __attribute__((ext_vector_type(4))) float f32x4;

__device__ __forceinline__ unsigned bf16rne(float f) {
    unsigned u = __float_as_uint(f);
    return (u + 0x7fffu + ((u >> 16) & 1u)) >> 16;
}
__device__ __forceinline__ unsigned pack_bf16x2(float lo, float hi) {
    return bf16rne(lo) | (bf16rne(hi) << 16);
}

// Features are row-major bf16 [node][64] (r6-proven fastest layout).

// ---------------- x -> bf16 conversion + gcursor zero + gstart ------------

__global__ void cvt_kernel(const float* __restrict__ x, unsigned short* __restrict__ xb,
                           int* __restrict__ gcursor, const int* __restrict__ batch,
                           int* __restrict__ gstart) {
    int i = blockIdx.x * blockDim.x + threadIdx.x;
    if (blockIdx.x == 0 && threadIdx.x < NP) gcursor[threadIdx.x] = 0;
    if (i < N_NODES) {
        int b = batch[i];
        int bp = (i > 0) ? batch[i - 1] : -1;
        for (int g = bp + 1; g <= b; ++g) gstart[g] = i;       // ~128 writes total
        if (i == N_NODES - 1)
            for (int g = b + 1; g <= N_GRAPHS; ++g) gstart[g] = N_NODES;
    }
    if (i < N_NODES * 16) {
        float4 v = ((const float4*)x)[i];
        uint2 o;
        o.x = pack_bf16x2(v.x, v.y);
        o.y = pack_bf16x2(v.z, v.w);
        ((uint2*)xb)[i] = o;
    }
}

// ---------------- CSR build: 2-level LDS-staged counting sort -------------
// (r2 lesson: flat atomic scatter = 90us of random-RMW; keep the LDS sort.)

__global__ __launch_bounds__(256) void bucket_kernel(
    const int* __restrict__ src, const int* __restrict__ dst,
    int* __restrict__ gcursor, unsigned* __restrict__ packed, int E) {
    __shared__ int hist[NP], scp[NP], base[NP], cnt2[NP];
    __shared__ int sc[256];
    __shared__ unsigned stag[EPA];
    const int t = threadIdx.x;
    const int e0 = blockIdx.x * EPA;
    const int e1 = min(e0 + EPA, E);
    for (int i = t; i < NP; i += 256) { hist[i] = 0; cnt2[i] = 0; }
    __syncthreads();
    for (int e = e0 + t; e < e1; e += 256)
        atomicAdd(&hist[dst[e] >> 8], 1);
    __syncthreads();
    sc[t] = (t < NP) ? hist[t] : 0;
    __syncthreads();
    for (int off = 1; off < 256; off <<= 1) {
        int add = (t >= off) ? sc[t - off] : 0;
        __syncthreads();
        sc[t] += add;
        __syncthreads();
    }
    if (t < NP) {
        scp[t] = sc[t] - hist[t];
        if (hist[t] > 0) base[t] = atomicAdd(&gcursor[t], hist[t]);
    }
    __syncthreads();
    for (int e = e0 + t; e < e1; e += 256) {
        int d = dst[e], s = src[e];
        int p = d >> 8;
        int idx = scp[p] + atomicAdd(&cnt2[p], 1);
        stag[idx] = (unsigned)s | ((unsigned)(d & 255) << 16) | ((unsigned)p << 24);
    }
    __syncthreads();
    const int n = e1 - e0;
    for (int i = t; i < n; i += 256) {
        unsigned v = stag[i];
        int p = v >> 24;
        packed[(size_t)p * PCAP + base[p] + (i - scp[p])] = v & 0x00FFFFFFu;
    }
}

// One block per partition. Integrated pscan, node offsets, LDS csr scatter,
// coalesced copy out. Block 0 also zeroes sums for the fused pooling.
__global__ __launch_bounds__(256) void build_kernel(
    const unsigned* __restrict__ packed, const int* __restrict__ gcursor,
    int* __restrict__ offsets, unsigned short* __restrict__ csr,
    int* __restrict__ sums_zero) {
    __shared__ int hist[256], lofs[256], cnt[256], sc[256], gv[256];
    __shared__ unsigned short lcsr[PCAP];
    const int p = blockIdx.x, t = threadIdx.x;

    if (p == 0) {   // zero sums(128*64 f32) for layer3's fused pooling
        for (int i = t; i < N_GRAPHS * 64; i += 256) sums_zero[i] = 0;
    }

    int v = (t < NP) ? gcursor[t] : 0;
    sc[t] = v; gv[t] = v;
    __syncthreads();
    for (int off = 1; off < 256; off <<= 1) {
        int add = (t >= off) ? sc[t - off] : 0;
        __syncthreads();
        sc[t] += add;
        __syncthreads();
    }
    const int pb = sc[p] - gv[p];          // exclusive prefix at p
    const int ne = gv[p];
    if (p == NP - 1 && t == 0) offsets[N_NODES] = sc[NP - 1];
    __syncthreads();

    const unsigned* mypk = packed + (size_t)p * PCAP;
    hist[t] = 0; cnt[t] = 0;
    __syncthreads();
    for (int i = t; i < ne; i += 256)
        atomicAdd(&hist[(mypk[i] >> 16) & 255], 1);
    __syncthreads();
    sc[t] = hist[t];
    __syncthreads();
    for (int off = 1; off < 256; off <<= 1) {
        int add = (t >= off) ? sc[t - off] : 0;
        __syncthreads();
        sc[t] += add;
        __syncthreads();
    }
    lofs[t] = sc[t] - hist[t];
    int node = p * 256 + t;
    if (node < N_NODES) offsets[node] = pb + lofs[t];
    __syncthreads();
    for (int i = t; i < ne; i += 256) {
        unsigned vv = mypk[i];
        int dl = (vv >> 16) & 255;
        int slot = lofs[dl] + atomicAdd(&cnt[dl], 1);
        lcsr[slot] = (unsigned short)(vv & 0xFFFFu);
    }
    __syncthreads();
    for (int i = t; i < ne; i += 256) csr[pb + i] = lcsr[i];
}

// ---------------- Fused layer: gather (r3 body) -> LDS -> MFMA -----------
// One wave owns 16 nodes: gathers them into agg_lds, then consumes them as
// MFMA A-fragments from LDS. No global agg round-trip, no inter-kernel
// drain between gather and linear. Weights staged once per block into LDS
// as pre-packed bf16 fragments (keeps VGPR lean). outT reuses agg_lds.

template <int RELU, int POOL>
__global__ __launch_bounds__(256) void layer_kernel(
    const unsigned short* __restrict__ hin,
    const int* __restrict__ offsets, const unsigned short* __restrict__ csr_src,
    const float* __restrict__ Wrel, const float* __restrict__ bias,
    const float* __restrict__ Wroot, unsigned short* __restrict__ hout,
    const int* __restrict__ batch, float* __restrict__ sums) {
    __shared__ short8 wfrag[2][4][2][4][16];       // [mat][t][s][q][c], 16KB
    __shared__ unsigned short agg_lds[64][72];     // gather out / outT reuse

    const int tid = threadIdx.x;
    const int w = tid >> 6, lane = tid & 63;
    const int g0 = (blockIdx.x * 4 + w) * 16;

    // ---- stage weight fragments to LDS (all waves participate) ----
    for (int f = tid; f < 1024; f += 256) {
        int m = f >> 9;
        int r = f & 511;
        int t = r >> 7, s = (r >> 6) & 1, q = (r >> 4) & 3, c = r & 15;
        const float* W = m ? Wroot : Wrel;
        const float4* pw = (const float4*)(W + (t * 16 + c) * 64 + s * 32 + q * 8);
        float4 v0 = pw[0], v1 = pw[1];
        short8 fr;
        fr[0] = (short)bf16rne(v0.x); fr[1] = (short)bf16rne(v0.y);
        fr[2] = (short)bf16rne(v0.z); fr[3] = (short)bf16rne(v0.w);
        fr[4] = (short)bf16rne(v1.x); fr[5] = (short)bf16rne(v1.y);
        fr[6] = (short)bf16rne(v1.z); fr[7] = (short)bf16rne(v1.w);
        wfrag[m][t][s][q][c] = fr;
    }

    // ---- gather phase: 16 nodes, r3-proven 1-node inner loop ----
    if (g0 < N_NODES) {
        const int rg = lane >> 3;          // row group: 8 rows per load instr
        const int cg = lane & 7;           // channel group: 8 ch (16 B)
        int myoff = (lane < 17) ? offsets[g0 + lane] : 0;
        for (int i = 0; i < 16; ++i) {
            const int beg = __shfl(myoff, i), end = __shfl(myoff, i + 1);
            float acc[8] = {0.f, 0.f, 0.f, 0.f, 0.f, 0.f, 0.f, 0.f};
            for (int base = beg; base < end; base += 64) {
                int cnt = min(64, end - base);
                int sidx = (base + lane < end) ? (int)csr_src[base + lane] : 0;
                for (int kb = 0; kb < cnt; kb += 32) {
                    uint4 u[4];
#pragma unroll
                    for (int p = 0; p < 4; ++p) {
                        int e = kb + 8 * p + rg;
                        int r = __shfl(sidx, e);
                        u[p] = (e < cnt) ? *((const uint4*)(hin + (size_t)r * 64) + cg)
                                         : make_uint4(0u, 0u, 0u, 0u);
                    }
#pragma unroll
                    for (int p = 0; p < 4; ++p) {
                        acc[0] += __uint_as_float(u[p].x << 16);
                        acc[1] += __uint_as_float(u[p].x & 0xffff0000u);
                        acc[2] += __uint_as_float(u[p].y << 16);
                        acc[3] += __uint_as_float(u[p].y & 0xffff0000u);
                        acc[4] += __uint_as_float(u[p].z << 16);
                        acc[5] += __uint_as_float(u[p].z & 0xffff0000u);
                        acc[6] += __uint_as_float(u[p].w << 16);
                        acc[7] += __uint_as_float(u[p].w & 0xffff0000u);
                    }
                }
            }
#pragma unroll
            for (int m = 8; m <= 32; m <<= 1)
#pragma unroll
                for (int j = 0; j < 8; ++j)
                    acc[j] += __shfl_xor(acc[j], m);
            if (rg == 0) {
                uint4 o;
                o.x = pack_bf16x2(acc[0], acc[1]);
                o.y = pack_bf16x2(acc[2], acc[3]);
                o.z = pack_bf16x2(acc[4], acc[5]);
                o.w = pack_bf16x2(acc[6], acc[7]);
                *((uint4*)&agg_lds[w * 16 + i][cg * 8]) = o;
            }
        }
    }

    __syncthreads();                       // wfrag ready (agg is wave-local)
    if (g0 >= N_NODES) return;

    // ---- linear phase: A from LDS (agg) + global (root) ----
    const int q = lane >> 4, c = lane & 15;
    short8 a_agg[2], a_x[2];
#pragma unroll
    for (int s = 0; s < 2; ++s) {
        a_agg[s] = *(const short8*)&agg_lds[w * 16 + c][s * 32 + q * 8];
        a_x[s]   = *(const short8*)(hin + (size_t)(g0 + c) * 64 + s * 32 + q * 8);
    }
    float biasv[4];
#pragma unroll
    for (int t = 0; t < 4; ++t) biasv[t] = bias[t * 16 + c];

    f32x4 acc4[4];
#pragma unroll
    for (int t = 0; t < 4; ++t) {
        f32x4 a0 = {biasv[t], biasv[t], biasv[t], biasv[t]};
        a0 = __builtin_amdgcn_mfma_f32_16x16x32_bf16(a_agg[0], wfrag[0][t][0][q][c], a0, 0, 0, 0);
        a0 = __builtin_amdgcn_mfma_f32_16x16x32_bf16(a_agg[1], wfrag[0][t][1][q][c], a0, 0, 0, 0);
        a0 = __builtin_amdgcn_mfma_f32_16x16x32_bf16(a_x[0],   wfrag[1][t][0][q][c], a0, 0, 0, 0);
        a0 = __builtin_amdgcn_mfma_f32_16x16x32_bf16(a_x[1],   wfrag[1][t][1][q][c], a0, 0, 0, 0);
        acc4[t] = a0;
    }

    if (POOL) {
        // batch sorted: wave's 16 nodes almost always one graph
        int b0 = batch[g0], b15 = batch[g0 + 15];
        if (b0 == b15) {
#pragma unroll
            for (int t = 0; t < 4; ++t) {
                float s = acc4[t][0] + acc4[t][1] + acc4[t][2] + acc4[t][3];
                s += __shfl_xor(s, 16);          // sum over q (lane bits 4-5)
                s += __shfl_xor(s, 32);
                if (q == 0) atomicAdd(&sums[b0 * 64 + t * 16 + c], s);
            }
        } else {                                  // graph boundary (~4% waves)
#pragma unroll
            for (int r = 0; r < 4; ++r) {
                int bq = batch[g0 + q * 4 + r];
#pragma unroll
                for (int t = 0; t < 4; ++t)
                    atomicAdd(&sums[bq * 64 + t * 16 + c], acc4[t][r]);
            }
        }
    } else {
        // ReLU + bf16 + per-wave LDS transpose; outT reuses agg_lds rows
        // (wave-local RAW: compiler orders via lgkmcnt; no barrier needed)
#pragma unroll
        for (int t = 0; t < 4; ++t)
#pragma unroll
            for (int r = 0; r < 4; ++r) {
                float v = acc4[t][r];
                if (RELU) v = fmaxf(v, 0.f);
                agg_lds[w * 16 + q * 4 + r][t * 16 + c] = (unsigned short)bf16rne(v);
            }
#pragma unroll
        for (int it = 0; it < 2; ++it) {
            int row = it * 8 + (lane >> 3);
            int ch = (lane & 7) * 8;
            short8 v = *(const short8*)&agg_lds[w * 16 + row][ch];
            *(short8*)(hout + (size_t)(g0 + row) * 64 + ch) = v;
        }
    }
}

// ---------------- Final: counts from gstart (no binary search) ------------

__global__ void final_kernel(const float* __restrict__ sums, const int* __restrict__ gstart,
                             const float* __restrict__ Wlin, const float* __restrict__ blin,
                             float* __restrict__ out) {
    __shared__ float pl[64];
    int g = blockIdx.x, lane = threadIdx.x;
    float cdiv = fmaxf((float)(gstart[g + 1] - gstart[g]), 1.0f);
    float p = sums[g * 64 + lane] / cdiv;
    out[g * 64 + lane] = p;               // pooled output
    pl[lane] = p;
    __syncthreads();
    if (lane < N_CLASSES) {
        float o = blin[lane];
#pragma unroll
        for (int k = 0; k < 64; ++k) o += pl[k] * Wlin[lane * 64 + k];
        out[N_GRAPHS * 64 + g * N_CLASSES + lane] = o;  // classifier output
    }
}

// ---------------- Launch (7 dispatches, no memsets) ----------------

extern "C" void kernel_launch(void* const* d_in, const int* in_sizes, int n_in,
                              void* d_out, int out_size, void* d_ws, size_t ws_size,
                              hipStream_t stream) {
    const float* x     = (const float*)d_in[0];
    const int*   ei    = (const int*)d_in[1];
    const int*   batch = (const int*)d_in[2];
    const float* W1r = (const float*)d_in[3];
    const float* b1  = (const float*)d_in[4];
    const float* W1o = (const float*)d_in[5];
    const float* W2r = (const float*)d_in[6];
    const float* b2  = (const float*)d_in[7];
    const float* W2o = (const float*)d_in[8];
    const float* W3r = (const float*)d_in[9];
    const float* b3  = (const float*)d_in[10];
    const float* W3o = (const float*)d_in[11];
    const float* Wl  = (const float*)d_in[12];
    const float* bl  = (const float*)d_in[13];
    float* out = (float*)d_out;

    const int E = in_sizes[1] / 2;
    const int* src = ei;
    const int* dst = ei + E;

    char* p = (char*)d_ws;
    unsigned short* xb  = (unsigned short*)p; p += (size_t)N_NODES * 64 * 2;
    unsigned short* h1  = (unsigned short*)p; p += (size_t)N_NODES * 64 * 2;
    unsigned short* h2  = (unsigned short*)p; p += (size_t)N_NODES * 64 * 2;
    unsigned* packed    = (unsigned*)p; p += (size_t)NP * PCAP * 4;
    unsigned short* csr = (unsigned short*)p; p += (size_t)E * 2;
    int* offsets   = (int*)p;   p += (size_t)(N_NODES + 1) * 4;
    int* gcursor   = (int*)p;   p += NP * 4;
    float* sums    = (float*)p; p += (size_t)N_GRAPHS * 64 * 4;
    int* gstart    = (int*)p;   p += (N_GRAPHS + 1) * 4;

    const int NCHUNK = (E + EPA - 1) / EPA;  // 153
    cvt_kernel<<<(N_NODES * 16 + 255) / 256, 256, 0, stream>>>(x, xb, gcursor, batch, gstart);
    bucket_kernel<<<NCHUNK, 256, 0, stream>>>(src, dst, gcursor, packed, E);
    build_kernel<<<NP, 256, 0, stream>>>(packed, gcursor, offsets, csr, (int*)sums);

    const int LB = (N_NODES + 63) / 64;    // 782 blocks, 4 waves x 16 nodes
    layer_kernel<1, 0><<<LB, 256, 0, stream>>>(xb, offsets, csr, W1r, b1, W1o, h1, batch, sums);
    layer_kernel<1, 0><<<LB, 256, 0, stream>>>(h1, offsets, csr, W2r, b2, W2o, h2, batch, sums);
    layer_kernel<0, 1><<<LB, 256, 0, stream>>>(h2, offsets, csr, W3r, b3, W3o, h1, batch, sums);

    final_kernel<<<N_GRAPHS, 64, 0, stream>>>(sums, gstart, Wl, bl, out);
}

// Round 6
// 248.530 us; speedup vs baseline: 1.0987x; 1.0091x over previous
//
#include <hip/hip_runtime.h>

#define N_NODES   50000
#define HID       64
#define N_GRAPHS  128
#define N_CLASSES 10
#define NP        196           // partitions of 256 nodes (196*256 = 50176)
#define EPA       8192          // edges per bucket block (r0-proven)
#define PCAP      8192          // per-partition capacity in packed[] (>20 sigma)

typedef __attribute__((ext_vector_type(8))) short short8;
typedef __attribute__((ext_vector_type(4))) float f32x4;

__device__ __forceinline__ unsigned bf16rne(float f) {
    unsigned u = __float_as_uint(f);
    return (u + 0x7fffu + ((u >> 16) & 1u)) >> 16;
}
__device__ __forceinline__ unsigned pack_bf16x2(float lo, float hi) {
    return bf16rne(lo) | (bf16rne(hi) << 16);
}

// Features are row-major bf16 [node][64] (r6-proven fastest layout).

// ---------------- x -> bf16 conversion + gcursor zero + gstart ------------

__global__ void cvt_kernel(const float* __restrict__ x, unsigned short* __restrict__ xb,
                           int* __restrict__ gcursor, const int* __restrict__ batch,
                           int* __restrict__ gstart) {
    int i = blockIdx.x * blockDim.x + threadIdx.x;
    if (blockIdx.x == 0 && threadIdx.x < NP) gcursor[threadIdx.x] = 0;
    if (i < N_NODES) {
        int b = batch[i];
        int bp = (i > 0) ? batch[i - 1] : -1;
        for (int g = bp + 1; g <= b; ++g) gstart[g] = i;       // ~128 writes total
        if (i == N_NODES - 1)
            for (int g = b + 1; g <= N_GRAPHS; ++g) gstart[g] = N_NODES;
    }
    if (i < N_NODES * 16) {
        float4 v = ((const float4*)x)[i];
        uint2 o;
        o.x = pack_bf16x2(v.x, v.y);
        o.y = pack_bf16x2(v.z, v.w);
        ((uint2*)xb)[i] = o;
    }
}

// ---------------- CSR build: 2-level LDS-staged counting sort -------------
// (r2 lesson: flat atomic scatter = 90us of random-RMW; keep the LDS sort.)

__global__ __launch_bounds__(256) void bucket_kernel(
    const int* __restrict__ src, const int* __restrict__ dst,
    int* __restrict__ gcursor, unsigned* __restrict__ packed, int E) {
    __shared__ int hist[NP], scp[NP], base[NP], cnt2[NP];
    __shared__ int sc[256];
    __shared__ unsigned stag[EPA];
    const int t = threadIdx.x;
    const int e0 = blockIdx.x * EPA;
    const int e1 = min(e0 + EPA, E);
    for (int i = t; i < NP; i += 256) { hist[i] = 0; cnt2[i] = 0; }
    __syncthreads();
    for (int e = e0 + t; e < e1; e += 256)
        atomicAdd(&hist[dst[e] >> 8], 1);
    __syncthreads();
    sc[t] = (t < NP) ? hist[t] : 0;
    __syncthreads();
    for (int off = 1; off < 256; off <<= 1) {
        int add = (t >= off) ? sc[t - off] : 0;
        __syncthreads();
        sc[t] += add;
        __syncthreads();
    }
    if (t < NP) {
        scp[t] = sc[t] - hist[t];
        if (hist[t] > 0) base[t] = atomicAdd(&gcursor[t], hist[t]);
    }
    __syncthreads();
    for (int e = e0 + t; e < e1; e += 256) {
        int d = dst[e], s = src[e];
        int p = d >> 8;
        int idx = scp[p] + atomicAdd(&cnt2[p], 1);
        stag[idx] = (unsigned)s | ((unsigned)(d & 255) << 16) | ((unsigned)p << 24);
    }
    __syncthreads();
    const int n = e1 - e0;
    for (int i = t; i < n; i += 256) {
        unsigned v = stag[i];
        int p = v >> 24;
        packed[(size_t)p * PCAP + base[p] + (i - scp[p])] = v & 0x00FFFFFFu;
    }
}

// One block per partition. Integrated pscan, node offsets, LDS csr scatter,
// coalesced copy out. Block 0 also zeroes sums for the fused pooling.
__global__ __launch_bounds__(256) void build_kernel(
    const unsigned* __restrict__ packed, const int* __restrict__ gcursor,
    int* __restrict__ offsets, unsigned short* __restrict__ csr,
    int* __restrict__ sums_zero) {
    __shared__ int hist[256], lofs[256], cnt[256], sc[256], gv[256];
    __shared__ unsigned short lcsr[PCAP];
    const int p = blockIdx.x, t = threadIdx.x;

    if (p == 0) {   // zero sums(128*64 f32) for layer3's fused pooling
        for (int i = t; i < N_GRAPHS * 64; i += 256) sums_zero[i] = 0;
    }

    int v = (t < NP) ? gcursor[t] : 0;
    sc[t] = v; gv[t] = v;
    __syncthreads();
    for (int off = 1; off < 256; off <<= 1) {
        int add = (t >= off) ? sc[t - off] : 0;
        __syncthreads();
        sc[t] += add;
        __syncthreads();
    }
    const int pb = sc[p] - gv[p];          // exclusive prefix at p
    const int ne = gv[p];
    if (p == NP - 1 && t == 0) offsets[N_NODES] = sc[NP - 1];
    __syncthreads();

    const unsigned* mypk = packed + (size_t)p * PCAP;
    hist[t] = 0; cnt[t] = 0;
    __syncthreads();
    for (int i = t; i < ne; i += 256)
        atomicAdd(&hist[(mypk[i] >> 16) & 255], 1);
    __syncthreads();
    sc[t] = hist[t];
    __syncthreads();
    for (int off = 1; off < 256; off <<= 1) {
        int add = (t >= off) ? sc[t - off] : 0;
        __syncthreads();
        sc[t] += add;
        __syncthreads();
    }
    lofs[t] = sc[t] - hist[t];
    int node = p * 256 + t;
    if (node < N_NODES) offsets[node] = pb + lofs[t];
    __syncthreads();
    for (int i = t; i < ne; i += 256) {
        unsigned vv = mypk[i];
        int dl = (vv >> 16) & 255;
        int slot = lofs[dl] + atomicAdd(&cnt[dl], 1);
        lcsr[slot] = (unsigned short)(vv & 0xFFFFu);
    }
    __syncthreads();
    for (int i = t; i < ne; i += 256) csr[pb + i] = lcsr[i];
}

// ---------------- Fused layer: paired gather -> LDS -> MFMA --------------
// One wave owns 16 nodes. Gather processes node PAIRS (r4 body): one 64-lane
// csr load feeds both halves, 8 dwordx4 row-loads in flight per round.
// Rationale (r5 counters): occupancy is grid-bound at ~12 waves/CU, so
// latency hiding must come from per-wave MLP, not TLP. (r4's same transform
// failed only because occupancy was TLP-saturated there.)

template <int RELU, int POOL>
__global__ __launch_bounds__(256) void layer_kernel(
    const unsigned short* __restrict__ hin,
    const int* __restrict__ offsets, const unsigned short* __restrict__ csr_src,
    const float* __restrict__ Wrel, const float* __restrict__ bias,
    const float* __restrict__ Wroot, unsigned short* __restrict__ hout,
    const int* __restrict__ batch, float* __restrict__ sums) {
    __shared__ short8 wfrag[2][4][2][4][16];       // [mat][t][s][q][c], 16KB
    __shared__ unsigned short agg_lds[64][72];     // gather out / outT reuse

    const int tid = threadIdx.x;
    const int w = tid >> 6, lane = tid & 63;
    const int g0 = (blockIdx.x * 4 + w) * 16;

    // ---- stage weight fragments to LDS (all waves participate) ----
    for (int f = tid; f < 1024; f += 256) {
        int m = f >> 9;
        int r = f & 511;
        int t = r >> 7, s = (r >> 6) & 1, q = (r >> 4) & 3, c = r & 15;
        const float* W = m ? Wroot : Wrel;
        const float4* pw = (const float4*)(W + (t * 16 + c) * 64 + s * 32 + q * 8);
        float4 v0 = pw[0], v1 = pw[1];
        short8 fr;
        fr[0] = (short)bf16rne(v0.x); fr[1] = (short)bf16rne(v0.y);
        fr[2] = (short)bf16rne(v0.z); fr[3] = (short)bf16rne(v0.w);
        fr[4] = (short)bf16rne(v1.x); fr[5] = (short)bf16rne(v1.y);
        fr[6] = (short)bf16rne(v1.z); fr[7] = (short)bf16rne(v1.w);
        wfrag[m][t][s][q][c] = fr;
    }

    // ---- gather phase: 8 node-pairs, 8 loads in flight per round ----
    if (g0 < N_NODES) {
        const int rg = lane >> 3;          // row group: 8 rows per load instr
        const int cg = lane & 7;           // channel group: 8 ch (16 B)
        int myoff = (lane < 17) ? offsets[g0 + lane] : 0;
        for (int i = 0; i < 8; ++i) {
            const int begA = __shfl(myoff, 2 * i);
            const int endA = __shfl(myoff, 2 * i + 1);
            const int endB = __shfl(myoff, 2 * i + 2);
            float accA[8] = {0.f,0.f,0.f,0.f,0.f,0.f,0.f,0.f};
            float accB[8] = {0.f,0.f,0.f,0.f,0.f,0.f,0.f,0.f};
            int eA = begA, eB = endA;
            while (eA < endA || eB < endB) {
                int cntA = endA - eA; cntA = (cntA > 32) ? 32 : cntA;
                int cntB = endB - eB; cntB = (cntB > 32) ? 32 : cntB;
                int idx;
                if (lane < 32) idx = (lane < cntA) ? (int)csr_src[eA + lane] : 0;
                else           idx = ((lane - 32) < cntB) ? (int)csr_src[eB + (lane - 32)] : 0;
                uint4 uA[4], uB[4];
#pragma unroll
                for (int p = 0; p < 4; ++p) {
                    int e = 8 * p + rg;
                    int rA = __shfl(idx, e);
                    uA[p] = (e < cntA) ? *((const uint4*)(hin + (size_t)rA * 64) + cg)
                                       : make_uint4(0u, 0u, 0u, 0u);
                }
#pragma unroll
                for (int p = 0; p < 4; ++p) {
                    int e = 8 * p + rg;
                    int rB = __shfl(idx, 32 + e);
                    uB[p] = (e < cntB) ? *((const uint4*)(hin + (size_t)rB * 64) + cg)
                                       : make_uint4(0u, 0u, 0u, 0u);
                }
#pragma unroll
                for (int p = 0; p < 4; ++p) {
                    accA[0] += __uint_as_float(uA[p].x << 16);
                    accA[1] += __uint_as_float(uA[p].x & 0xffff0000u);
                    accA[2] += __uint_as_float(uA[p].y << 16);
                    accA[3] += __uint_as_float(uA[p].y & 0xffff0000u);
                    accA[4] += __uint_as_float(uA[p].z << 16);
                    accA[5] += __uint_as_float(uA[p].z & 0xffff0000u);
                    accA[6] += __uint_as_float(uA[p].w << 16);
                    accA[7] += __uint_as_float(uA[p].w & 0xffff0000u);
                    accB[0] += __uint_as_float(uB[p].x << 16);
                    accB[1] += __uint_as_float(uB[p].x & 0xffff0000u);
                    accB[2] += __uint_as_float(uB[p].y << 16);
                    accB[3] += __uint_as_float(uB[p].y & 0xffff0000u);
                    accB[4] += __uint_as_float(uB[p].z << 16);
                    accB[5] += __uint_as_float(uB[p].z & 0xffff0000u);
                    accB[6] += __uint_as_float(uB[p].w << 16);
                    accB[7] += __uint_as_float(uB[p].w & 0xffff0000u);
                }
                eA += cntA; eB += cntB;
            }
#pragma unroll
            for (int m = 8; m <= 32; m <<= 1)
#pragma unroll
                for (int j = 0; j < 8; ++j) {
                    accA[j] += __shfl_xor(accA[j], m);
                    accB[j] += __shfl_xor(accB[j], m);
                }
            if (rg == 0) {
                uint4 o;
                o.x = pack_bf16x2(accA[0], accA[1]);
                o.y = pack_bf16x2(accA[2], accA[3]);
                o.z = pack_bf16x2(accA[4], accA[5]);
                o.w = pack_bf16x2(accA[6], accA[7]);
                *((uint4*)&agg_lds[w * 16 + 2 * i][cg * 8]) = o;
            } else if (rg == 1) {
                uint4 o;
                o.x = pack_bf16x2(accB[0], accB[1]);
                o.y = pack_bf16x2(accB[2], accB[3]);
                o.z = pack_bf16x2(accB[4], accB[5]);
                o.w = pack_bf16x2(accB[6], accB[7]);
                *((uint4*)&agg_lds[w * 16 + 2 * i + 1][cg * 8]) = o;
            }
        }
    }

    __syncthreads();                       // wfrag ready (agg is wave-local)
    if (g0 >= N_NODES) return;

    // ---- linear phase: A from LDS (agg) + global (root) ----
    const int q = lane >> 4, c = lane & 15;
    short8 a_agg[2], a_x[2];
#pragma unroll
    for (int s = 0; s < 2; ++s) {
        a_agg[s] = *(const short8*)&agg_lds[w * 16 + c][s * 32 + q * 8];
        a_x[s]   = *(const short8*)(hin + (size_t)(g0 + c) * 64 + s * 32 + q * 8);
    }
    float biasv[4];
#pragma unroll
    for (int t = 0; t < 4; ++t) biasv[t] = bias[t * 16 + c];

    f32x4 acc4[4];
#pragma unroll
    for (int t = 0; t < 4; ++t) {
        f32x4 a0 = {biasv[t], biasv[t], biasv[t], biasv[t]};
        a0 = __builtin_amdgcn_mfma_f32_16x16x32_bf16(a_agg[0], wfrag[0][t][0][q][c], a0, 0, 0, 0);
        a0 = __builtin_amdgcn_mfma_f32_16x16x32_bf16(a_agg[1], wfrag[0][t][1][q][c], a0, 0, 0, 0);
        a0 = __builtin_amdgcn_mfma_f32_16x16x32_bf16(a_x[0],   wfrag[1][t][0][q][c], a0, 0, 0, 0);
        a0 = __builtin_amdgcn_mfma_f32_16x16x32_bf16(a_x[1],   wfrag[1][t][1][q][c], a0, 0, 0, 0);
        acc4[t] = a0;
    }

    if (POOL) {
        // batch sorted: wave's 16 nodes almost always one graph
        int b0 = batch[g0], b15 = batch[g0 + 15];
        if (b0 == b15) {
#pragma unroll
            for (int t = 0; t < 4; ++t) {
                float s = acc4[t][0] + acc4[t][1] + acc4[t][2] + acc4[t][3];
                s += __shfl_xor(s, 16);          // sum over q (lane bits 4-5)
                s += __shfl_xor(s, 32);
                if (q == 0) atomicAdd(&sums[b0 * 64 + t * 16 + c], s);
            }
        } else {                                  // graph boundary (~4% waves)
#pragma unroll
            for (int r = 0; r < 4; ++r) {
                int bq = batch[g0 + q * 4 + r];
#pragma unroll
                for (int t = 0; t < 4; ++t)
                    atomicAdd(&sums[bq * 64 + t * 16 + c], acc4[t][r]);
            }
        }
    } else {
        // ReLU + bf16 + per-wave LDS transpose; outT reuses agg_lds rows
        // (wave-local RAW: compiler orders via lgkmcnt; no barrier needed)
#pragma unroll
        for (int t = 0; t < 4; ++t)
#pragma unroll
            for (int r = 0; r < 4; ++r) {
                float v = acc4[t][r];
                if (RELU) v = fmaxf(v, 0.f);
                agg_lds[w * 16 + q * 4 + r][t * 16 + c] = (unsigned short)bf16rne(v);
            }
#pragma unroll
        for (int it = 0; it < 2; ++it) {
            int row = it * 8 + (lane >> 3);
            int ch = (lane & 7) * 8;
            short8 v = *(const short8*)&agg_lds[w * 16 + row][ch];
            *(short8*)(hout + (size_t)(g0 + row) * 64 + ch) = v;
        }
    }
}

// ---------------- Final: counts from gstart (no binary search) ------------

__global__ void final_kernel(const float* __restrict__ sums, const int* __restrict__ gstart,
                             const float* __restrict__ Wlin, const float* __restrict__ blin,
                             float* __restrict__ out) {
    __shared__ float pl[64];
    int g = blockIdx.x, lane = threadIdx.x;
    float cdiv = fmaxf((float)(gstart[g + 1] - gstart[g]), 1.0f);
    float p = sums[g * 64 + lane] / cdiv;
    out[g * 64 + lane] = p;               // pooled output
    pl[lane] = p;
    __syncthreads();
    if (lane < N_CLASSES) {
        float o = blin[lane];
#pragma unroll
        for (int k = 0; k < 64; ++k) o += pl[k] * Wlin[lane * 64 + k];
        out[N_GRAPHS * 64 + g * N_CLASSES + lane] = o;  // classifier output
    }
}

// ---------------- Launch (7 dispatches, no memsets) ----------------

extern "C" void kernel_launch(void* const* d_in, const int* in_sizes, int n_in,
                              void* d_out, int out_size, void* d_ws, size_t ws_size,
                              hipStream_t stream) {
    const float* x     = (const float*)d_in[0];
    const int*   ei    = (const int*)d_in[1];
    const int*   batch = (const int*)d_in[2];
    const float* W1r = (const float*)d_in[3];
    const float* b1  = (const float*)d_in[4];
    const float* W1o = (const float*)d_in[5];
    const float* W2r = (const float*)d_in[6];
    const float* b2  = (const float*)d_in[7];
    const float* W2o = (const float*)d_in[8];
    const float* W3r = (const float*)d_in[9];
    const float* b3  = (const float*)d_in[10];
    const float* W3o = (const float*)d_in[11];
    const float* Wl  = (const float*)d_in[12];
    const float* bl  = (const float*)d_in[13];
    float* out = (float*)d_out;

    const int E = in_sizes[1] / 2;
    const int* src = ei;
    const int* dst = ei + E;

    char* p = (char*)d_ws;
    unsigned short* xb  = (unsigned short*)p; p += (size_t)N_NODES * 64 * 2;
    unsigned short* h1  = (unsigned short*)p; p += (size_t)N_NODES * 64 * 2;
    unsigned short* h2  = (unsigned short*)p; p += (size_t)N_NODES * 64 * 2;
    unsigned* packed    = (unsigned*)p; p += (size_t)NP * PCAP * 4;
    unsigned short* csr = (unsigned short*)p; p += (size_t)E * 2;
    int* offsets   = (int*)p;   p += (size_t)(N_NODES + 1) * 4;
    int* gcursor   = (int*)p;   p += NP * 4;
    float* sums    = (float*)p; p += (size_t)N_GRAPHS * 64 * 4;
    int* gstart    = (int*)p;   p += (N_GRAPHS + 1) * 4;

    const int NCHUNK = (E + EPA - 1) / EPA;  // 153
    cvt_kernel<<<(N_NODES * 16 + 255) / 256, 256, 0, stream>>>(x, xb, gcursor, batch, gstart);
    bucket_kernel<<<NCHUNK, 256, 0, stream>>>(src, dst, gcursor, packed, E);
    build_kernel<<<NP, 256, 0, stream>>>(packed, gcursor, offsets, csr, (int*)sums);

    const int LB = (N_NODES + 63) / 64;    // 782 blocks, 4 waves x 16 nodes
    layer_kernel<1, 0><<<LB, 256, 0, stream>>>(xb, offsets, csr, W1r, b1, W1o, h1, batch, sums);
    layer_kernel<1, 0><<<LB, 256, 0, stream>>>(h1, offsets, csr, W2r, b2, W2o, h2, batch, sums);
    layer_kernel<0, 1><<<LB, 256, 0, stream>>>(h2, offsets, csr, W3r, b3, W3o, h1, batch, sums);

    final_kernel<<<N_GRAPHS, 64, 0, stream>>>(sums, gstart, Wl, bl, out);
}

// Round 7
// 234.191 us; speedup vs baseline: 1.1660x; 1.0612x over previous
//
#include <hip/hip_runtime.h>

#define N_NODES   50000
#define HID       64
#define N_GRAPHS  128
#define N_CLASSES 10
#define NP        196           // partitions of 256 nodes (196*256 = 50176)
#define EPA       8192          // edges per bucket block (r0-proven)
#define PCAP      8192          // per-partition capacity in packed[] (>20 sigma)

typedef __attribute__((ext_vector_type(8))) short short8;
typedef __attribute__((ext_vector_type(4))) float f32x4;

__device__ __forceinline__ unsigned bf16rne(float f) {
    unsigned u = __float_as_uint(f);
    return (u + 0x7fffu + ((u >> 16) & 1u)) >> 16;
}
__device__ __forceinline__ unsigned pack_bf16x2(float lo, float hi) {
    return bf16rne(lo) | (bf16rne(hi) << 16);
}

// Features are row-major bf16 [node][64] (r6-proven fastest layout).

// ---------------- x -> bf16 conversion + gcursor zero + gstart ------------

__global__ void cvt_kernel(const float* __restrict__ x, unsigned short* __restrict__ xb,
                           int* __restrict__ gcursor, const int* __restrict__ batch,
                           int* __restrict__ gstart) {
    int i = blockIdx.x * blockDim.x + threadIdx.x;
    if (blockIdx.x == 0 && threadIdx.x < NP) gcursor[threadIdx.x] = 0;
    if (i < N_NODES) {
        int b = batch[i];
        int bp = (i > 0) ? batch[i - 1] : -1;
        for (int g = bp + 1; g <= b; ++g) gstart[g] = i;       // ~128 writes total
        if (i == N_NODES - 1)
            for (int g = b + 1; g <= N_GRAPHS; ++g) gstart[g] = N_NODES;
    }
    if (i < N_NODES * 16) {
        float4 v = ((const float4*)x)[i];
        uint2 o;
        o.x = pack_bf16x2(v.x, v.y);
        o.y = pack_bf16x2(v.z, v.w);
        ((uint2*)xb)[i] = o;
    }
}

// ---------------- CSR build: 2-level LDS-staged counting sort -------------
// (r2 lesson: flat atomic scatter = 90us of random-RMW; keep the LDS sort.)

__global__ __launch_bounds__(256) void bucket_kernel(
    const int* __restrict__ src, const int* __restrict__ dst,
    int* __restrict__ gcursor, unsigned* __restrict__ packed, int E) {
    __shared__ int hist[NP], scp[NP], base[NP], cnt2[NP];
    __shared__ int sc[256];
    __shared__ unsigned stag[EPA];
    const int t = threadIdx.x;
    const int e0 = blockIdx.x * EPA;
    const int e1 = min(e0 + EPA, E);
    for (int i = t; i < NP; i += 256) { hist[i] = 0; cnt2[i] = 0; }
    __syncthreads();
    for (int e = e0 + t; e < e1; e += 256)
        atomicAdd(&hist[dst[e] >> 8], 1);
    __syncthreads();
    sc[t] = (t < NP) ? hist[t] : 0;
    __syncthreads();
    for (int off = 1; off < 256; off <<= 1) {
        int add = (t >= off) ? sc[t - off] : 0;
        __syncthreads();
        sc[t] += add;
        __syncthreads();
    }
    if (t < NP) {
        scp[t] = sc[t] - hist[t];
        if (hist[t] > 0) base[t] = atomicAdd(&gcursor[t], hist[t]);
    }
    __syncthreads();
    for (int e = e0 + t; e < e1; e += 256) {
        int d = dst[e], s = src[e];
        int p = d >> 8;
        int idx = scp[p] + atomicAdd(&cnt2[p], 1);
        stag[idx] = (unsigned)s | ((unsigned)(d & 255) << 16) | ((unsigned)p << 24);
    }
    __syncthreads();
    const int n = e1 - e0;
    for (int i = t; i < n; i += 256) {
        unsigned v = stag[i];
        int p = v >> 24;
        packed[(size_t)p * PCAP + base[p] + (i - scp[p])] = v & 0x00FFFFFFu;
    }
}

// One block per partition. Integrated pscan, node offsets, LDS csr scatter,
// coalesced copy out. Block 0 also zeroes sums for the fused pooling.
__global__ __launch_bounds__(256) void build_kernel(
    const unsigned* __restrict__ packed, const int* __restrict__ gcursor,
    int* __restrict__ offsets, unsigned short* __restrict__ csr,
    int* __restrict__ sums_zero) {
    __shared__ int hist[256], lofs[256], cnt[256], sc[256], gv[256];
    __shared__ unsigned short lcsr[PCAP];
    const int p = blockIdx.x, t = threadIdx.x;

    if (p == 0) {   // zero sums(128*64 f32) for layer3's fused pooling
        for (int i = t; i < N_GRAPHS * 64; i += 256) sums_zero[i] = 0;
    }

    int v = (t < NP) ? gcursor[t] : 0;
    sc[t] = v; gv[t] = v;
    __syncthreads();
    for (int off = 1; off < 256; off <<= 1) {
        int add = (t >= off) ? sc[t - off] : 0;
        __syncthreads();
        sc[t] += add;
        __syncthreads();
    }
    const int pb = sc[p] - gv[p];          // exclusive prefix at p
    const int ne = gv[p];
    if (p == NP - 1 && t == 0) offsets[N_NODES] = sc[NP - 1];
    __syncthreads();

    const unsigned* mypk = packed + (size_t)p * PCAP;
    hist[t] = 0; cnt[t] = 0;
    __syncthreads();
    for (int i = t; i < ne; i += 256)
        atomicAdd(&hist[(mypk[i] >> 16) & 255], 1);
    __syncthreads();
    sc[t] = hist[t];
    __syncthreads();
    for (int off = 1; off < 256; off <<= 1) {
        int add = (t >= off) ? sc[t - off] : 0;
        __syncthreads();
        sc[t] += add;
        __syncthreads();
    }
    lofs[t] = sc[t] - hist[t];
    int node = p * 256 + t;
    if (node < N_NODES) offsets[node] = pb + lofs[t];
    __syncthreads();
    for (int i = t; i < ne; i += 256) {
        unsigned vv = mypk[i];
        int dl = (vv >> 16) & 255;
        int slot = lofs[dl] + atomicAdd(&cnt[dl], 1);
        lcsr[slot] = (unsigned short)(vv & 0xFFFFu);
    }
    __syncthreads();
    for (int i = t; i < ne; i += 256) csr[pb + i] = lcsr[i];
}

// ---------------- Fused layer: 32 nodes/block, wave-pair MFMA ------------
// r6 lesson: in-wave MLP restructuring is null; the binding constraint is
// grid-imposed occupancy (782 blocks = 12 waves/CU, 21% occupancy). Halve
// work per block: 4 waves x 8 nodes gather (1563 blocks, ~24 waves/CU).
// MFMA needs 16 rows -> waves pair up: both read the same A (agg via LDS),
// each computes half the output channels (2 of 4 t-values).

template <int RELU, int POOL>
__global__ __launch_bounds__(256) void layer_kernel(
    const unsigned short* __restrict__ hin,
    const int* __restrict__ offsets, const unsigned short* __restrict__ csr_src,
    const float* __restrict__ Wrel, const float* __restrict__ bias,
    const float* __restrict__ Wroot, unsigned short* __restrict__ hout,
    const int* __restrict__ batch, float* __restrict__ sums) {
    __shared__ short8 wfrag[2][4][2][4][16];       // [mat][t][s][q][c], 16KB
    __shared__ unsigned short agg_lds[32][72];     // gather out / outT reuse

    const int tid = threadIdx.x;
    const int w = tid >> 6, lane = tid & 63;
    const int g0 = blockIdx.x * 32;                // block's first node

    // ---- stage weight fragments to LDS (all waves participate) ----
    for (int f = tid; f < 1024; f += 256) {
        int m = f >> 9;
        int r = f & 511;
        int t = r >> 7, s = (r >> 6) & 1, q = (r >> 4) & 3, c = r & 15;
        const float* W = m ? Wroot : Wrel;
        const float4* pw = (const float4*)(W + (t * 16 + c) * 64 + s * 32 + q * 8);
        float4 v0 = pw[0], v1 = pw[1];
        short8 fr;
        fr[0] = (short)bf16rne(v0.x); fr[1] = (short)bf16rne(v0.y);
        fr[2] = (short)bf16rne(v0.z); fr[3] = (short)bf16rne(v0.w);
        fr[4] = (short)bf16rne(v1.x); fr[5] = (short)bf16rne(v1.y);
        fr[6] = (short)bf16rne(v1.z); fr[7] = (short)bf16rne(v1.w);
        wfrag[m][t][s][q][c] = fr;
    }

    // ---- gather phase: each wave owns 8 nodes (r5-proven 1-node body) ----
    {
        const int rg = lane >> 3;          // row group: 8 rows per load instr
        const int cg = lane & 7;           // channel group: 8 ch (16 B)
        const int nb = g0 + w * 8;         // wave's first node
        int myoff = (lane < 9) ? offsets[min(nb + lane, N_NODES)] : 0;
        for (int i = 0; i < 8; ++i) {
            const int beg = __shfl(myoff, i), end = __shfl(myoff, i + 1);
            float acc[8] = {0.f, 0.f, 0.f, 0.f, 0.f, 0.f, 0.f, 0.f};
            for (int base = beg; base < end; base += 64) {
                int cnt = min(64, end - base);
                int sidx = (base + lane < end) ? (int)csr_src[base + lane] : 0;
                for (int kb = 0; kb < cnt; kb += 32) {
                    uint4 u[4];
#pragma unroll
                    for (int p = 0; p < 4; ++p) {
                        int e = kb + 8 * p + rg;
                        int r = __shfl(sidx, e);
                        u[p] = (e < cnt) ? *((const uint4*)(hin + (size_t)r * 64) + cg)
                                         : make_uint4(0u, 0u, 0u, 0u);
                    }
#pragma unroll
                    for (int p = 0; p < 4; ++p) {
                        acc[0] += __uint_as_float(u[p].x << 16);
                        acc[1] += __uint_as_float(u[p].x & 0xffff0000u);
                        acc[2] += __uint_as_float(u[p].y << 16);
                        acc[3] += __uint_as_float(u[p].y & 0xffff0000u);
                        acc[4] += __uint_as_float(u[p].z << 16);
                        acc[5] += __uint_as_float(u[p].z & 0xffff0000u);
                        acc[6] += __uint_as_float(u[p].w << 16);
                        acc[7] += __uint_as_float(u[p].w & 0xffff0000u);
                    }
                }
            }
#pragma unroll
            for (int m = 8; m <= 32; m <<= 1)
#pragma unroll
                for (int j = 0; j < 8; ++j)
                    acc[j] += __shfl_xor(acc[j], m);
            if (rg == 0) {
                uint4 o;
                o.x = pack_bf16x2(acc[0], acc[1]);
                o.y = pack_bf16x2(acc[2], acc[3]);
                o.z = pack_bf16x2(acc[4], acc[5]);
                o.w = pack_bf16x2(acc[6], acc[7]);
                *((uint4*)&agg_lds[w * 8 + i][cg * 8]) = o;
            }
        }
    }

    __syncthreads();                       // wfrag + cross-wave agg ready

    // ---- linear phase: wave-pair shares A, splits output channels ----
    const int ng = w >> 1;                 // node group: rows ng*16..+15
    const int th = w & 1;                  // t-half: t = th*2 + {0,1}
    const int q = lane >> 4, c = lane & 15;
    const int n0 = g0 + ng * 16;

    short8 a_agg[2], a_x[2];
#pragma unroll
    for (int s = 0; s < 2; ++s) {
        a_agg[s] = *(const short8*)&agg_lds[ng * 16 + c][s * 32 + q * 8];
        a_x[s]   = *(const short8*)(hin + (size_t)min(n0 + c, N_NODES - 1) * 64 + s * 32 + q * 8);
    }

    f32x4 acc4[2];
#pragma unroll
    for (int tt = 0; tt < 2; ++tt) {
        const int t = th * 2 + tt;
        float bv = bias[t * 16 + c];
        f32x4 a0 = {bv, bv, bv, bv};
        a0 = __builtin_amdgcn_mfma_f32_16x16x32_bf16(a_agg[0], wfrag[0][t][0][q][c], a0, 0, 0, 0);
        a0 = __builtin_amdgcn_mfma_f32_16x16x32_bf16(a_agg[1], wfrag[0][t][1][q][c], a0, 0, 0, 0);
        a0 = __builtin_amdgcn_mfma_f32_16x16x32_bf16(a_x[0],   wfrag[1][t][0][q][c], a0, 0, 0, 0);
        a0 = __builtin_amdgcn_mfma_f32_16x16x32_bf16(a_x[1],   wfrag[1][t][1][q][c], a0, 0, 0, 0);
        acc4[tt] = a0;
    }

    if (POOL) {
        // batch sorted: 16-node group almost always one graph
        int nlast = n0 + 15;
        int b0 = batch[min(n0, N_NODES - 1)];
        int b15 = (nlast < N_NODES) ? batch[nlast] : -1;
        if (b0 == b15) {
#pragma unroll
            for (int tt = 0; tt < 2; ++tt) {
                const int t = th * 2 + tt;
                float s = acc4[tt][0] + acc4[tt][1] + acc4[tt][2] + acc4[tt][3];
                s += __shfl_xor(s, 16);          // sum over q (lane bits 4-5)
                s += __shfl_xor(s, 32);
                if (q == 0) atomicAdd(&sums[b0 * 64 + t * 16 + c], s);
            }
        } else {                                  // boundary / tail waves
#pragma unroll
            for (int r = 0; r < 4; ++r) {
                int n = n0 + q * 4 + r;
                if (n < N_NODES) {
                    int bq = batch[n];
#pragma unroll
                    for (int tt = 0; tt < 2; ++tt)
                        atomicAdd(&sums[bq * 64 + (th * 2 + tt) * 16 + c], acc4[tt][r]);
                }
            }
        }
    } else {
        __syncthreads();   // pair partner done reading A from agg_lds
        // ReLU + bf16 transpose into agg_lds (rows=node, ch=t*16+c)
#pragma unroll
        for (int tt = 0; tt < 2; ++tt) {
            const int t = th * 2 + tt;
#pragma unroll
            for (int r = 0; r < 4; ++r) {
                float v = acc4[tt][r];
                if (RELU) v = fmaxf(v, 0.f);
                agg_lds[ng * 16 + q * 4 + r][t * 16 + c] = (unsigned short)bf16rne(v);
            }
        }
        __syncthreads();   // rows assembled across the pair
        // store: wave w writes rows w*8..w*8+7, full 64 ch, short8
        {
            int row = w * 8 + (lane >> 3);
            int ch = (lane & 7) * 8;
            int n = g0 + row;
            if (n < N_NODES) {
                short8 v = *(const short8*)&agg_lds[row][ch];
                *(short8*)(hout + (size_t)n * 64 + ch) = v;
            }
        }
    }
}

// ---------------- Final: counts from gstart (no binary search) ------------

__global__ void final_kernel(const float* __restrict__ sums, const int* __restrict__ gstart,
                             const float* __restrict__ Wlin, const float* __restrict__ blin,
                             float* __restrict__ out) {
    __shared__ float pl[64];
    int g = blockIdx.x, lane = threadIdx.x;
    float cdiv = fmaxf((float)(gstart[g + 1] - gstart[g]), 1.0f);
    float p = sums[g * 64 + lane] / cdiv;
    out[g * 64 + lane] = p;               // pooled output
    pl[lane] = p;
    __syncthreads();
    if (lane < N_CLASSES) {
        float o = blin[lane];
#pragma unroll
        for (int k = 0; k < 64; ++k) o += pl[k] * Wlin[lane * 64 + k];
        out[N_GRAPHS * 64 + g * N_CLASSES + lane] = o;  // classifier output
    }
}

// ---------------- Launch (7 dispatches, no memsets) ----------------

extern "C" void kernel_launch(void* const* d_in, const int* in_sizes, int n_in,
                              void* d_out, int out_size, void* d_ws, size_t ws_size,
                              hipStream_t stream) {
    const float* x     = (const float*)d_in[0];
    const int*   ei    = (const int*)d_in[1];
    const int*   batch = (const int*)d_in[2];
    const float* W1r = (const float*)d_in[3];
    const float* b1  = (const float*)d_in[4];
    const float* W1o = (const float*)d_in[5];
    const float* W2r = (const float*)d_in[6];
    const float* b2  = (const float*)d_in[7];
    const float* W2o = (const float*)d_in[8];
    const float* W3r = (const float*)d_in[9];
    const float* b3  = (const float*)d_in[10];
    const float* W3o = (const float*)d_in[11];
    const float* Wl  = (const float*)d_in[12];
    const float* bl  = (const float*)d_in[13];
    float* out = (float*)d_out;

    const int E = in_sizes[1] / 2;
    const int* src = ei;
    const int* dst = ei + E;

    char* p = (char*)d_ws;
    unsigned short* xb  = (unsigned short*)p; p += (size_t)N_NODES * 64 * 2;
    unsigned short* h1  = (unsigned short*)p; p += (size_t)N_NODES * 64 * 2;
    unsigned short* h2  = (unsigned short*)p; p += (size_t)N_NODES * 64 * 2;
    unsigned* packed    = (unsigned*)p; p += (size_t)NP * PCAP * 4;
    unsigned short* csr = (unsigned short*)p; p += (size_t)E * 2;
    int* offsets   = (int*)p;   p += (size_t)(N_NODES + 1) * 4;
    int* gcursor   = (int*)p;   p += NP * 4;
    float* sums    = (float*)p; p += (size_t)N_GRAPHS * 64 * 4;
    int* gstart    = (int*)p;   p += (N_GRAPHS + 1) * 4;

    const int NCHUNK = (E + EPA - 1) / EPA;  // 153
    cvt_kernel<<<(N_NODES * 16 + 255) / 256, 256, 0, stream>>>(x, xb, gcursor, batch, gstart);
    bucket_kernel<<<NCHUNK, 256, 0, stream>>>(src, dst, gcursor, packed, E);
    build_kernel<<<NP, 256, 0, stream>>>(packed, gcursor, offsets, csr, (int*)sums);

    const int LB = (N_NODES + 31) / 32;    // 1563 blocks, 4 waves x 8 nodes
    layer_kernel<1, 0><<<LB, 256, 0, stream>>>(xb, offsets, csr, W1r, b1, W1o, h1, batch, sums);
    layer_kernel<1, 0><<<LB, 256, 0, stream>>>(h1, offsets, csr, W2r, b2, W2o, h2, batch, sums);
    layer_kernel<0, 1><<<LB, 256, 0, stream>>>(h2, offsets, csr, W3r, b3, W3o, h1, batch, sums);

    final_kernel<<<N_GRAPHS, 64, 0, stream>>>(sums, gstart, Wl, bl, out);
}